// Round 1
// baseline (800.812 us; speedup 1.0000x reference)
//
#include <hip/hip_runtime.h>

// GCN forward: 3x (GEMM -> normalized scatter-sum -> bias -> relu[except last])
// Strategy: build CSR-by-destination once per launch (same adjacency for all
// layers), then aggregate with one wave per node (lane = feature), no atomics
// in the hot loops.

#define ALIGN256(x) (((size_t)(x) + 255) & ~(size_t)255)

// ---------------- CSR construction ----------------

__global__ __launch_bounds__(256) void k_count(const int* __restrict__ ei,
                                               int* __restrict__ cnt, int E) {
    int e = blockIdx.x * 256 + threadIdx.x;
    if (e < E) atomicAdd(&cnt[ei[E + e]], 1);   // dst = ei[1][e]
}

__global__ __launch_bounds__(256) void k_dinv(const int* __restrict__ cnt,
                                              float* __restrict__ dinv, int N) {
    int i = blockIdx.x * 256 + threadIdx.x;
    if (i < N) dinv[i] = 1.0f / sqrtf((float)(cnt[i] + 1));  // +1 self-loop; deg>=1
}

// block scans 1024 elements (256 threads x 4); writes exclusive prefix + block sum
__global__ __launch_bounds__(256) void k_scan1(const int* __restrict__ cnt,
                                               int* __restrict__ row_start,
                                               int* __restrict__ blksum, int N) {
    __shared__ int sd[256];
    int t = threadIdx.x;
    int base = blockIdx.x * 1024 + t * 4;
    int e[4];
    int s = 0;
#pragma unroll
    for (int i = 0; i < 4; i++) {
        int idx = base + i;
        e[i] = (idx < N) ? cnt[idx] : 0;
        s += e[i];
    }
    sd[t] = s;
    __syncthreads();
    for (int off = 1; off < 256; off <<= 1) {
        int v = (t >= off) ? sd[t - off] : 0;
        __syncthreads();
        sd[t] += v;
        __syncthreads();
    }
    int run = sd[t] - s;  // exclusive prefix of this thread's chunk
#pragma unroll
    for (int i = 0; i < 4; i++) {
        int idx = base + i;
        if (idx < N) row_start[idx] = run;
        run += e[i];
    }
    if (t == 0) blksum[blockIdx.x] = sd[255];
}

// single block: exclusive-scan the (<=256) block sums in place
__global__ __launch_bounds__(256) void k_scan2(int* __restrict__ blksum, int NB) {
    __shared__ int sd[256];
    int t = threadIdx.x;
    int v = (t < NB) ? blksum[t] : 0;
    sd[t] = v;
    __syncthreads();
    for (int off = 1; off < 256; off <<= 1) {
        int u = (t >= off) ? sd[t - off] : 0;
        __syncthreads();
        sd[t] += u;
        __syncthreads();
    }
    if (t < NB) blksum[t] = sd[t] - v;
}

__global__ __launch_bounds__(256) void k_scan3(int* __restrict__ row_start,
                                               int* __restrict__ pos,
                                               const int* __restrict__ blkoff,
                                               int N, int E) {
    int i = blockIdx.x * 256 + threadIdx.x;
    if (i < N) {
        int v = row_start[i] + blkoff[i >> 10];
        row_start[i] = v;
        pos[i] = v;
    }
    if (i == 0) row_start[N] = E;
}

__global__ __launch_bounds__(256) void k_bucket(const int* __restrict__ ei,
                                                const float* __restrict__ dinv,
                                                int* __restrict__ pos,
                                                int* __restrict__ esrc,
                                                float* __restrict__ enorm, int E) {
    int e = blockIdx.x * 256 + threadIdx.x;
    if (e >= E) return;
    int s = ei[e];
    int d = ei[E + e];
    int slot = atomicAdd(&pos[d], 1);
    esrc[slot] = s;
    enorm[slot] = dinv[s] * dinv[d];
}

// ---------------- GEMM: Y[N,OUT] = X[N,K] @ W[K,OUT] ----------------
// 64 rows x 64 cols per 256-thread block, 4x4 register tile, K tiled by 32.
// K in {64,128}; OUT <= 64, OUT % 4 == 0. W zero-padded to 64 cols in LDS.

__global__ __launch_bounds__(256) void k_gemm(const float* __restrict__ X,
                                              const float* __restrict__ W,
                                              float* __restrict__ Y,
                                              int N, int K, int OUT) {
    __shared__ float Wl[128 * 64];   // 32 KB max
    __shared__ float Al[64 * 36];    // 9 KB, padded stride 36 (16B-aligned)
    int tid = threadIdx.x;
    int tx = tid & 15;       // col group: cols 4*tx .. 4*tx+3
    int ty = tid >> 4;       // row group: rows 4*ty .. 4*ty+3
    int row0 = blockIdx.x * 64;

    for (int idx = tid; idx < K * 64; idx += 256) {
        int k = idx >> 6, c = idx & 63;
        Wl[idx] = (c < OUT) ? W[k * OUT + c] : 0.0f;
    }

    float acc[4][4];
#pragma unroll
    for (int i = 0; i < 4; i++)
#pragma unroll
        for (int j = 0; j < 4; j++) acc[i][j] = 0.0f;

    for (int kt = 0; kt < K; kt += 32) {
        __syncthreads();
#pragma unroll
        for (int it = 0; it < 2; it++) {
            int vid = tid + it * 256;       // 0..511 float4 slots (64 rows x 8)
            int r = vid >> 3;
            int kk = (vid & 7) << 2;
            int row = row0 + r;
            float4 v = make_float4(0.f, 0.f, 0.f, 0.f);
            if (row < N) v = *(const float4*)&X[(size_t)row * K + kt + kk];
            *(float4*)&Al[r * 36 + kk] = v;
        }
        __syncthreads();
#pragma unroll
        for (int k = 0; k < 32; k += 4) {
            float4 a[4], w[4];
#pragma unroll
            for (int i = 0; i < 4; i++) a[i] = *(const float4*)&Al[(4 * ty + i) * 36 + k];
#pragma unroll
            for (int j = 0; j < 4; j++) w[j] = *(const float4*)&Wl[(kt + k + j) * 64 + 4 * tx];
#pragma unroll
            for (int i = 0; i < 4; i++) {
                acc[i][0] += a[i].x * w[0].x; acc[i][1] += a[i].x * w[0].y;
                acc[i][2] += a[i].x * w[0].z; acc[i][3] += a[i].x * w[0].w;
                acc[i][0] += a[i].y * w[1].x; acc[i][1] += a[i].y * w[1].y;
                acc[i][2] += a[i].y * w[1].z; acc[i][3] += a[i].y * w[1].w;
                acc[i][0] += a[i].z * w[2].x; acc[i][1] += a[i].z * w[2].y;
                acc[i][2] += a[i].z * w[2].z; acc[i][3] += a[i].z * w[2].w;
                acc[i][0] += a[i].w * w[3].x; acc[i][1] += a[i].w * w[3].y;
                acc[i][2] += a[i].w * w[3].z; acc[i][3] += a[i].w * w[3].w;
            }
        }
    }

    int c0 = 4 * tx;
#pragma unroll
    for (int i = 0; i < 4; i++) {
        int row = row0 + 4 * ty + i;
        if (row < N && c0 + 4 <= OUT) {
            *(float4*)&Y[(size_t)row * OUT + c0] =
                make_float4(acc[i][0], acc[i][1], acc[i][2], acc[i][3]);
        }
    }
}

// ---------------- Aggregation: out[d] = sum_{e: dst=d} H[src]*norm + self + b ----
// one wave (64 lanes) per node; lane = feature index

__global__ __launch_bounds__(256) void k_agg(const float* __restrict__ H,
                                             const int* __restrict__ row_start,
                                             const int* __restrict__ esrc,
                                             const float* __restrict__ enorm,
                                             const float* __restrict__ dinv,
                                             const float* __restrict__ bias,
                                             float* __restrict__ out,
                                             int N, int F, int relu) {
    int wid = (blockIdx.x * 256 + threadIdx.x) >> 6;
    int lane = threadIdx.x & 63;
    if (wid >= N) return;
    int n = wid;
    int jb = row_start[n];
    int je = row_start[n + 1];
    float dv = dinv[n];
    // self-loop term (reads lane in [0,64); H buffers are N*64 floats so in-bounds)
    float acc = H[(size_t)n * F + lane] * dv * dv;
    for (int j = jb; j < je; j++) {
        int s = esrc[j];
        float w = enorm[j];
        acc += H[(size_t)s * F + lane] * w;
    }
    if (lane < F) {
        acc += bias[lane];
        if (relu) acc = fmaxf(acc, 0.0f);
        out[(size_t)n * F + lane] = acc;
    }
}

// ---------------- launch ----------------

extern "C" void kernel_launch(void* const* d_in, const int* in_sizes, int n_in,
                              void* d_out, int out_size, void* d_ws, size_t ws_size,
                              hipStream_t stream) {
    const float* x  = (const float*)d_in[0];
    const int*   ei = (const int*)d_in[1];
    const float* W0 = (const float*)d_in[2];
    const float* b0 = (const float*)d_in[3];
    const float* W1 = (const float*)d_in[4];
    const float* b1 = (const float*)d_in[5];
    const float* W2 = (const float*)d_in[6];
    const float* b2 = (const float*)d_in[7];
    float* out = (float*)d_out;

    const int N = in_sizes[0] / 128;
    const int E = in_sizes[1] / 2;

    // workspace carve-up (256B aligned)
    char* w = (char*)d_ws;
    size_t off = 0;
    int*   cnt       = (int*)(w + off); off = ALIGN256(off + (size_t)N * 4);
    int*   row_start = (int*)(w + off); off = ALIGN256(off + (size_t)(N + 1) * 4);
    int*   pos       = (int*)(w + off); off = ALIGN256(off + (size_t)N * 4);
    float* dinv      = (float*)(w + off); off = ALIGN256(off + (size_t)N * 4);
    int*   blk       = (int*)(w + off); off = ALIGN256(off + 256 * 4);
    int*   esrc      = (int*)(w + off); off = ALIGN256(off + (size_t)E * 4);
    float* enorm     = (float*)(w + off); off = ALIGN256(off + (size_t)E * 4);
    float* bufA      = (float*)(w + off); off = ALIGN256(off + (size_t)N * 64 * 4);
    float* bufB      = (float*)(w + off); off = ALIGN256(off + (size_t)N * 64 * 4);

    const int gE = (E + 255) / 256;
    const int gN = (N + 255) / 256;
    const int NB = (N + 1023) / 1024;

    hipMemsetAsync(cnt, 0, (size_t)N * 4, stream);
    k_count<<<gE, 256, 0, stream>>>(ei, cnt, E);
    k_dinv<<<gN, 256, 0, stream>>>(cnt, dinv, N);
    k_scan1<<<NB, 256, 0, stream>>>(cnt, row_start, blk, N);
    k_scan2<<<1, 256, 0, stream>>>(blk, NB);
    k_scan3<<<gN, 256, 0, stream>>>(row_start, pos, blk, N, E);
    k_bucket<<<gE, 256, 0, stream>>>(ei, dinv, pos, esrc, enorm, E);

    const int gGemm = (N + 63) / 64;
    const int gAgg  = (N * 64 + 255) / 256;

    // layer 1: x[ N,128] @ W0 -> bufA ; agg+b0+relu -> bufB
    k_gemm<<<gGemm, 256, 0, stream>>>(x, W0, bufA, N, 128, 64);
    k_agg<<<gAgg, 256, 0, stream>>>(bufA, row_start, esrc, enorm, dinv, b0, bufB, N, 64, 1);
    // layer 2
    k_gemm<<<gGemm, 256, 0, stream>>>(bufB, W1, bufA, N, 64, 64);
    k_agg<<<gAgg, 256, 0, stream>>>(bufA, row_start, esrc, enorm, dinv, b1, bufB, N, 64, 1);
    // layer 3 (no relu), OUT=40
    k_gemm<<<gGemm, 256, 0, stream>>>(bufB, W2, bufA, N, 64, 40);
    k_agg<<<gAgg, 256, 0, stream>>>(bufA, row_start, esrc, enorm, dinv, b2, out, N, 40, 0);
}

// Round 2
// 516.048 us; speedup vs baseline: 1.5518x; 1.5518x over previous
//
#include <hip/hip_runtime.h>

// GCN forward: 3x (GEMM -> normalized scatter-sum -> bias -> relu[except last])
// CSR-by-destination built once per launch; aggregation uses 16-lane subgroups
// (4 nodes per wave, float4 per lane) for 4x memory-level parallelism.

#define ALIGN256(x) (((size_t)(x) + 255) & ~(size_t)255)

// ---------------- CSR construction ----------------

__global__ __launch_bounds__(256) void k_count(const int* __restrict__ ei,
                                               int* __restrict__ cnt, int E) {
    int e = blockIdx.x * 256 + threadIdx.x;
    if (e < E) atomicAdd(&cnt[ei[E + e]], 1);   // dst = ei[1][e]
}

__global__ __launch_bounds__(256) void k_dinv(const int* __restrict__ cnt,
                                              float* __restrict__ dinv, int N) {
    int i = blockIdx.x * 256 + threadIdx.x;
    if (i < N) dinv[i] = 1.0f / sqrtf((float)(cnt[i] + 1));  // +1 self-loop
}

// block scans 1024 elements (256 threads x 4); exclusive prefix + block sum
__global__ __launch_bounds__(256) void k_scan1(const int* __restrict__ cnt,
                                               int* __restrict__ row_start,
                                               int* __restrict__ blksum, int N) {
    __shared__ int sd[256];
    int t = threadIdx.x;
    int base = blockIdx.x * 1024 + t * 4;
    int e[4];
    int s = 0;
#pragma unroll
    for (int i = 0; i < 4; i++) {
        int idx = base + i;
        e[i] = (idx < N) ? cnt[idx] : 0;
        s += e[i];
    }
    sd[t] = s;
    __syncthreads();
    for (int off = 1; off < 256; off <<= 1) {
        int v = (t >= off) ? sd[t - off] : 0;
        __syncthreads();
        sd[t] += v;
        __syncthreads();
    }
    int run = sd[t] - s;
#pragma unroll
    for (int i = 0; i < 4; i++) {
        int idx = base + i;
        if (idx < N) row_start[idx] = run;
        run += e[i];
    }
    if (t == 0) blksum[blockIdx.x] = sd[255];
}

__global__ __launch_bounds__(256) void k_scan2(int* __restrict__ blksum, int NB) {
    __shared__ int sd[256];
    int t = threadIdx.x;
    int v = (t < NB) ? blksum[t] : 0;
    sd[t] = v;
    __syncthreads();
    for (int off = 1; off < 256; off <<= 1) {
        int u = (t >= off) ? sd[t - off] : 0;
        __syncthreads();
        sd[t] += u;
        __syncthreads();
    }
    if (t < NB) blksum[t] = sd[t] - v;
}

__global__ __launch_bounds__(256) void k_scan3(int* __restrict__ row_start,
                                               int* __restrict__ pos,
                                               const int* __restrict__ blkoff,
                                               int N, int E) {
    int i = blockIdx.x * 256 + threadIdx.x;
    if (i < N) {
        int v = row_start[i] + blkoff[i >> 10];
        row_start[i] = v;
        pos[i] = v;
    }
    if (i == 0) row_start[N] = E;
}

// one 8B store per edge: (src, bits(norm)) packed
__global__ __launch_bounds__(256) void k_bucket(const int* __restrict__ ei,
                                                const float* __restrict__ dinv,
                                                int* __restrict__ pos,
                                                int2* __restrict__ ep, int E) {
    int e = blockIdx.x * 256 + threadIdx.x;
    if (e >= E) return;
    int s = ei[e];
    int d = ei[E + e];
    int slot = atomicAdd(&pos[d], 1);
    ep[slot] = make_int2(s, __float_as_int(dinv[s] * dinv[d]));
}

// ---------------- GEMM: Y[N,OUT] = X[N,K] @ W[K,OUT] ----------------
// 64 rows x 64 cols per 256-thread block, 4x4 register tile, K tiled by 32.
// Thread rows are {ty, ty+16, ty+32, ty+48} so A-tile LDS reads spread over
// all 32 banks (row-major stride 36: bank = (4*ty + 16*i + k) % 32 -> 2-way max).

__global__ __launch_bounds__(256) void k_gemm(const float* __restrict__ X,
                                              const float* __restrict__ W,
                                              float* __restrict__ Y,
                                              int N, int K, int OUT) {
    __shared__ float Wl[128 * 64];   // 32 KB max
    __shared__ float Al[64 * 36];    // 9 KB, padded stride 36 (16B-aligned)
    int tid = threadIdx.x;
    int tx = tid & 15;       // col group: cols 4*tx .. 4*tx+3
    int ty = tid >> 4;       // row group: rows ty+16*i
    int row0 = blockIdx.x * 64;

    for (int idx = tid; idx < K * 64; idx += 256) {
        int k = idx >> 6, c = idx & 63;
        Wl[idx] = (c < OUT) ? W[k * OUT + c] : 0.0f;
    }

    float acc[4][4];
#pragma unroll
    for (int i = 0; i < 4; i++)
#pragma unroll
        for (int j = 0; j < 4; j++) acc[i][j] = 0.0f;

    for (int kt = 0; kt < K; kt += 32) {
        __syncthreads();
#pragma unroll
        for (int it = 0; it < 2; it++) {
            int vid = tid + it * 256;       // 0..511 float4 slots (64 rows x 8)
            int r = vid >> 3;
            int kk = (vid & 7) << 2;
            int row = row0 + r;
            float4 v = make_float4(0.f, 0.f, 0.f, 0.f);
            if (row < N) v = *(const float4*)&X[(size_t)row * K + kt + kk];
            *(float4*)&Al[r * 36 + kk] = v;
        }
        __syncthreads();
#pragma unroll
        for (int k = 0; k < 32; k += 4) {
            float4 a[4], w[4];
#pragma unroll
            for (int i = 0; i < 4; i++) a[i] = *(const float4*)&Al[(ty + 16 * i) * 36 + k];
#pragma unroll
            for (int j = 0; j < 4; j++) w[j] = *(const float4*)&Wl[(kt + k + j) * 64 + 4 * tx];
#pragma unroll
            for (int i = 0; i < 4; i++) {
                acc[i][0] += a[i].x * w[0].x; acc[i][1] += a[i].x * w[0].y;
                acc[i][2] += a[i].x * w[0].z; acc[i][3] += a[i].x * w[0].w;
                acc[i][0] += a[i].y * w[1].x; acc[i][1] += a[i].y * w[1].y;
                acc[i][2] += a[i].y * w[1].z; acc[i][3] += a[i].y * w[1].w;
                acc[i][0] += a[i].z * w[2].x; acc[i][1] += a[i].z * w[2].y;
                acc[i][2] += a[i].z * w[2].z; acc[i][3] += a[i].z * w[2].w;
                acc[i][0] += a[i].w * w[3].x; acc[i][1] += a[i].w * w[3].y;
                acc[i][2] += a[i].w * w[3].z; acc[i][3] += a[i].w * w[3].w;
            }
        }
    }

    int c0 = 4 * tx;
#pragma unroll
    for (int i = 0; i < 4; i++) {
        int row = row0 + ty + 16 * i;
        if (row < N && c0 + 4 <= OUT) {
            *(float4*)&Y[(size_t)row * OUT + c0] =
                make_float4(acc[i][0], acc[i][1], acc[i][2], acc[i][3]);
        }
    }
}

// ---------------- Aggregation ----------------
// 16 lanes per node (lane = float4 of features), 4 nodes per wave, 16 nodes
// per 256-thread block. Edge loop unrolled x4 with upfront (src,norm) loads:
// up to 16 independent gathers in flight per wave.

template <int NV, int F, int RELU>
__global__ __launch_bounds__(256) void k_agg4(const float* __restrict__ H,
                                              const int* __restrict__ row_start,
                                              const int2* __restrict__ ep,
                                              const float* __restrict__ dinv,
                                              const float* __restrict__ bias,
                                              float* __restrict__ out, int N) {
    int tid = threadIdx.x;
    int lane = tid & 63;
    int sub = lane >> 4;         // node within wave
    int lq = lane & 15;          // float4 index within node row
    int node = blockIdx.x * 16 + (tid >> 6) * 4 + sub;
    if (node >= N) return;
    const bool act = (lq < NV);

    int jb = row_start[node];
    int je = row_start[node + 1];
    float dv = dinv[node];

    float4 acc = make_float4(0.f, 0.f, 0.f, 0.f);
    if (act) {
        float4 h = *(const float4*)&H[(size_t)node * F + 4 * lq];
        float s2 = dv * dv;
        acc.x = h.x * s2; acc.y = h.y * s2; acc.z = h.z * s2; acc.w = h.w * s2;
    }

    int j = jb;
    for (; j + 4 <= je; j += 4) {
        int2 e0 = ep[j], e1 = ep[j + 1], e2 = ep[j + 2], e3 = ep[j + 3];
        if (act) {
            float4 h0 = *(const float4*)&H[(size_t)e0.x * F + 4 * lq];
            float4 h1 = *(const float4*)&H[(size_t)e1.x * F + 4 * lq];
            float4 h2 = *(const float4*)&H[(size_t)e2.x * F + 4 * lq];
            float4 h3 = *(const float4*)&H[(size_t)e3.x * F + 4 * lq];
            float w0 = __int_as_float(e0.y), w1 = __int_as_float(e1.y);
            float w2 = __int_as_float(e2.y), w3 = __int_as_float(e3.y);
            acc.x += h0.x * w0; acc.y += h0.y * w0; acc.z += h0.z * w0; acc.w += h0.w * w0;
            acc.x += h1.x * w1; acc.y += h1.y * w1; acc.z += h1.z * w1; acc.w += h1.w * w1;
            acc.x += h2.x * w2; acc.y += h2.y * w2; acc.z += h2.z * w2; acc.w += h2.w * w2;
            acc.x += h3.x * w3; acc.y += h3.y * w3; acc.z += h3.z * w3; acc.w += h3.w * w3;
        }
    }
    for (; j < je; j++) {
        int2 e = ep[j];
        if (act) {
            float4 h = *(const float4*)&H[(size_t)e.x * F + 4 * lq];
            float wv = __int_as_float(e.y);
            acc.x += h.x * wv; acc.y += h.y * wv; acc.z += h.z * wv; acc.w += h.w * wv;
        }
    }

    if (act) {
        float4 b = *(const float4*)&bias[4 * lq];
        acc.x += b.x; acc.y += b.y; acc.z += b.z; acc.w += b.w;
        if (RELU) {
            acc.x = fmaxf(acc.x, 0.f); acc.y = fmaxf(acc.y, 0.f);
            acc.z = fmaxf(acc.z, 0.f); acc.w = fmaxf(acc.w, 0.f);
        }
        *(float4*)&out[(size_t)node * F + 4 * lq] = acc;
    }
}

// ---------------- launch ----------------

extern "C" void kernel_launch(void* const* d_in, const int* in_sizes, int n_in,
                              void* d_out, int out_size, void* d_ws, size_t ws_size,
                              hipStream_t stream) {
    const float* x  = (const float*)d_in[0];
    const int*   ei = (const int*)d_in[1];
    const float* W0 = (const float*)d_in[2];
    const float* b0 = (const float*)d_in[3];
    const float* W1 = (const float*)d_in[4];
    const float* b1 = (const float*)d_in[5];
    const float* W2 = (const float*)d_in[6];
    const float* b2 = (const float*)d_in[7];
    float* out = (float*)d_out;

    const int N = in_sizes[0] / 128;
    const int E = in_sizes[1] / 2;

    char* w = (char*)d_ws;
    size_t off = 0;
    int*   cnt       = (int*)(w + off);   off = ALIGN256(off + (size_t)N * 4);
    int*   row_start = (int*)(w + off);   off = ALIGN256(off + (size_t)(N + 1) * 4);
    int*   pos       = (int*)(w + off);   off = ALIGN256(off + (size_t)N * 4);
    float* dinv      = (float*)(w + off); off = ALIGN256(off + (size_t)N * 4);
    int*   blk       = (int*)(w + off);   off = ALIGN256(off + 256 * 4);
    int2*  ep        = (int2*)(w + off);  off = ALIGN256(off + (size_t)E * 8);
    float* bufA      = (float*)(w + off); off = ALIGN256(off + (size_t)N * 64 * 4);
    float* bufB      = (float*)(w + off); off = ALIGN256(off + (size_t)N * 64 * 4);

    const int gE = (E + 255) / 256;
    const int gN = (N + 255) / 256;
    const int NB = (N + 1023) / 1024;

    hipMemsetAsync(cnt, 0, (size_t)N * 4, stream);
    k_count<<<gE, 256, 0, stream>>>(ei, cnt, E);
    k_dinv<<<gN, 256, 0, stream>>>(cnt, dinv, N);
    k_scan1<<<NB, 256, 0, stream>>>(cnt, row_start, blk, N);
    k_scan2<<<1, 256, 0, stream>>>(blk, NB);
    k_scan3<<<gN, 256, 0, stream>>>(row_start, pos, blk, N, E);
    k_bucket<<<gE, 256, 0, stream>>>(ei, dinv, pos, ep, E);

    const int gGemm = (N + 63) / 64;
    const int gAgg  = (N + 15) / 16;

    k_gemm<<<gGemm, 256, 0, stream>>>(x, W0, bufA, N, 128, 64);
    k_agg4<16, 64, 1><<<gAgg, 256, 0, stream>>>(bufA, row_start, ep, dinv, b0, bufB, N);
    k_gemm<<<gGemm, 256, 0, stream>>>(bufB, W1, bufA, N, 64, 64);
    k_agg4<16, 64, 1><<<gAgg, 256, 0, stream>>>(bufA, row_start, ep, dinv, b1, bufB, N);
    k_gemm<<<gGemm, 256, 0, stream>>>(bufB, W2, bufA, N, 64, 40);
    k_agg4<10, 40, 0><<<gAgg, 256, 0, stream>>>(bufA, row_start, ep, dinv, b2, out, N);
}

// Round 3
// 484.932 us; speedup vs baseline: 1.6514x; 1.0642x over previous
//
#include <hip/hip_runtime.h>

// GCN forward: 3x (GEMM -> normalized scatter-sum -> bias -> relu[except last])
// CSR-by-destination built once per launch via a 2-pass LDS-staged partition
// (coarse 256-node buckets, then in-bucket fine scatter) to avoid the
// 1-line-per-edge write-allocate blowup of a naive atomic bucket scatter.
// deg-count is fused into the (independent) layer-1 GEMM.

#define ALIGN256(x) (((size_t)(x) + 255) & ~(size_t)255)

// ---------------- scan: per-node counts -> row_start (exclusive prefix) -----

// block scans 1024 elements (256 threads x 4); exclusive prefix + block sum.
// also emits dinv = 1/sqrt(deg+1) (self-loop) for free.
__global__ __launch_bounds__(256) void k_scan1(const int* __restrict__ cnt,
                                               int* __restrict__ row_start,
                                               int* __restrict__ blksum,
                                               float* __restrict__ dinv, int N) {
    __shared__ int sd[256];
    int t = threadIdx.x;
    int base = blockIdx.x * 1024 + t * 4;
    int e[4];
    int s = 0;
#pragma unroll
    for (int i = 0; i < 4; i++) {
        int idx = base + i;
        e[i] = (idx < N) ? cnt[idx] : 0;
        if (idx < N) dinv[idx] = 1.0f / sqrtf((float)(e[i] + 1));
        s += e[i];
    }
    sd[t] = s;
    __syncthreads();
    for (int off = 1; off < 256; off <<= 1) {
        int v = (t >= off) ? sd[t - off] : 0;
        __syncthreads();
        sd[t] += v;
        __syncthreads();
    }
    int run = sd[t] - s;
#pragma unroll
    for (int i = 0; i < 4; i++) {
        int idx = base + i;
        if (idx < N) row_start[idx] = run;
        run += e[i];
    }
    if (t == 0) blksum[blockIdx.x] = sd[255];
}

__global__ __launch_bounds__(256) void k_scan2(int* __restrict__ blksum, int NB) {
    __shared__ int sd[256];
    int t = threadIdx.x;
    int v = (t < NB) ? blksum[t] : 0;
    sd[t] = v;
    __syncthreads();
    for (int off = 1; off < 256; off <<= 1) {
        int u = (t >= off) ? sd[t - off] : 0;
        __syncthreads();
        sd[t] += u;
        __syncthreads();
    }
    if (t < NB) blksum[t] = sd[t] - v;
}

// finalize row_start; emit coarse-bucket append pointers (one per 256 nodes)
__global__ __launch_bounds__(256) void k_scan3(int* __restrict__ row_start,
                                               const int* __restrict__ blkoff,
                                               int* __restrict__ cpos,
                                               int N, int E) {
    int i = blockIdx.x * 256 + threadIdx.x;
    if (i < N) {
        int v = row_start[i] + blkoff[i >> 10];
        row_start[i] = v;
        if ((i & 255) == 0) cpos[i >> 8] = v;
    }
    if (i == 0) row_start[N] = E;
}

// ---------------- partition pass A: coarse scatter (LDS-staged runs) --------
// Each block handles 8192 edges: LDS histogram over <=512 coarse buckets,
// one global atomicAdd per (block,bucket), then contiguous-run writes of
// (src,dst) into the bucket's stage region -> full cache lines.

__global__ __launch_bounds__(256) void k_passA(const int* __restrict__ ei,
                                               int* __restrict__ cpos,
                                               int2* __restrict__ stage,
                                               int E, int NBUK) {
    __shared__ int h[512];
    __shared__ int base[512];
    int t = threadIdx.x;
    for (int i = t; i < NBUK; i += 256) h[i] = 0;
    __syncthreads();
    int e0 = blockIdx.x * 8192;
    int e1 = min(e0 + 8192, E);
    for (int e = e0 + t; e < e1; e += 256) {
        int d = ei[E + e];
        atomicAdd(&h[d >> 8], 1);
    }
    __syncthreads();
    for (int b = t; b < NBUK; b += 256) {
        int c = h[b];
        base[b] = c ? atomicAdd(&cpos[b], c) : 0;
        h[b] = 0;
    }
    __syncthreads();
    for (int e = e0 + t; e < e1; e += 256) {
        int s = ei[e];
        int d = ei[E + e];
        int b = d >> 8;
        int off = base[b] + atomicAdd(&h[b], 1);
        stage[off] = make_int2(s, d);
    }
}

// ---------------- partition pass B: fine scatter within one bucket ----------
// One block per coarse bucket; per-node positions live in LDS; all ep writes
// land in this bucket's ~32KB region -> L2-resident, lines fully written.

__global__ __launch_bounds__(256) void k_passB(const int2* __restrict__ stage,
                                               const int* __restrict__ row_start,
                                               const float* __restrict__ dinv,
                                               int2* __restrict__ ep, int N) {
    __shared__ int lpos[256];
    __shared__ float ld[256];
    int b = blockIdx.x;
    int n0 = b << 8;
    int n1 = min(n0 + 256, N);
    int t = threadIdx.x;
    if (n0 + t < n1) {
        lpos[t] = row_start[n0 + t];
        ld[t] = dinv[n0 + t];
    }
    __syncthreads();
    int s0 = row_start[n0];
    int s1 = row_start[n1];     // row_start[N] == E
    for (int j = s0 + t; j < s1; j += 256) {
        int2 sd = stage[j];
        int li = sd.y - n0;
        int slot = atomicAdd(&lpos[li], 1);
        ep[slot] = make_int2(sd.x, __float_as_int(dinv[sd.x] * ld[li]));
    }
}

// ---------------- GEMM (+ fused degree count on extra blocks) ---------------
// 64 rows x 64 cols per 256-thread block, 4x4 register tile, K tiled by 32.
// Thread rows {ty, ty+16, ty+32, ty+48}: A-tile LDS reads spread all 32 banks.
// Blocks >= gemmBlocks instead run the (independent) per-dst degree count.

__global__ __launch_bounds__(256) void k_gemm(const float* __restrict__ X,
                                              const float* __restrict__ W,
                                              float* __restrict__ Y,
                                              int N, int K, int OUT,
                                              int gemmBlocks,
                                              const int* __restrict__ ei,
                                              int* __restrict__ cnt, int E) {
    __shared__ float Wl[128 * 64];   // 32 KB max
    __shared__ float Al[64 * 36];    // 9 KB, padded stride 36
    int tid = threadIdx.x;

    if ((int)blockIdx.x >= gemmBlocks) {
        // degree-count branch (whole block uniform; no barrier hazard)
        int e = (blockIdx.x - gemmBlocks) * 256 + tid;
        if (e < E) atomicAdd(&cnt[ei[E + e]], 1);
        return;
    }

    int tx = tid & 15;
    int ty = tid >> 4;
    int row0 = blockIdx.x * 64;

    for (int idx = tid; idx < K * 64; idx += 256) {
        int k = idx >> 6, c = idx & 63;
        Wl[idx] = (c < OUT) ? W[k * OUT + c] : 0.0f;
    }

    float acc[4][4];
#pragma unroll
    for (int i = 0; i < 4; i++)
#pragma unroll
        for (int j = 0; j < 4; j++) acc[i][j] = 0.0f;

    for (int kt = 0; kt < K; kt += 32) {
        __syncthreads();
#pragma unroll
        for (int it = 0; it < 2; it++) {
            int vid = tid + it * 256;       // 64 rows x 8 float4 slots
            int r = vid >> 3;
            int kk = (vid & 7) << 2;
            int row = row0 + r;
            float4 v = make_float4(0.f, 0.f, 0.f, 0.f);
            if (row < N) v = *(const float4*)&X[(size_t)row * K + kt + kk];
            *(float4*)&Al[r * 36 + kk] = v;
        }
        __syncthreads();
#pragma unroll
        for (int k = 0; k < 32; k += 4) {
            float4 a[4], w[4];
#pragma unroll
            for (int i = 0; i < 4; i++) a[i] = *(const float4*)&Al[(ty + 16 * i) * 36 + k];
#pragma unroll
            for (int j = 0; j < 4; j++) w[j] = *(const float4*)&Wl[(kt + k + j) * 64 + 4 * tx];
#pragma unroll
            for (int i = 0; i < 4; i++) {
                acc[i][0] += a[i].x * w[0].x; acc[i][1] += a[i].x * w[0].y;
                acc[i][2] += a[i].x * w[0].z; acc[i][3] += a[i].x * w[0].w;
                acc[i][0] += a[i].y * w[1].x; acc[i][1] += a[i].y * w[1].y;
                acc[i][2] += a[i].y * w[1].z; acc[i][3] += a[i].y * w[1].w;
                acc[i][0] += a[i].z * w[2].x; acc[i][1] += a[i].z * w[2].y;
                acc[i][2] += a[i].z * w[2].z; acc[i][3] += a[i].z * w[2].w;
                acc[i][0] += a[i].w * w[3].x; acc[i][1] += a[i].w * w[3].y;
                acc[i][2] += a[i].w * w[3].z; acc[i][3] += a[i].w * w[3].w;
            }
        }
    }

    int c0 = 4 * tx;
#pragma unroll
    for (int i = 0; i < 4; i++) {
        int row = row0 + ty + 16 * i;
        if (row < N && c0 + 4 <= OUT) {
            *(float4*)&Y[(size_t)row * OUT + c0] =
                make_float4(acc[i][0], acc[i][1], acc[i][2], acc[i][3]);
        }
    }
}

// ---------------- Aggregation ----------------
// 16 lanes per node (lane = float4 of features), 4 nodes/wave, unroll x8:
// up to 32 independent gathers in flight per wave.

template <int NV, int F, int RELU>
__global__ __launch_bounds__(256) void k_agg4(const float* __restrict__ H,
                                              const int* __restrict__ row_start,
                                              const int2* __restrict__ ep,
                                              const float* __restrict__ dinv,
                                              const float* __restrict__ bias,
                                              float* __restrict__ out, int N) {
    int tid = threadIdx.x;
    int lane = tid & 63;
    int sub = lane >> 4;
    int lq = lane & 15;
    int node = blockIdx.x * 16 + (tid >> 6) * 4 + sub;
    if (node >= N) return;
    const bool act = (lq < NV);

    int jb = row_start[node];
    int je = row_start[node + 1];
    float dv = dinv[node];

    float4 acc = make_float4(0.f, 0.f, 0.f, 0.f);
    if (act) {
        float4 h = *(const float4*)&H[(size_t)node * F + 4 * lq];
        float s2 = dv * dv;
        acc.x = h.x * s2; acc.y = h.y * s2; acc.z = h.z * s2; acc.w = h.w * s2;
    }

    int j = jb;
    for (; j + 8 <= je; j += 8) {
        int2 e0 = ep[j],     e1 = ep[j + 1], e2 = ep[j + 2], e3 = ep[j + 3];
        int2 e4 = ep[j + 4], e5 = ep[j + 5], e6 = ep[j + 6], e7 = ep[j + 7];
        if (act) {
            float4 h0 = *(const float4*)&H[(size_t)e0.x * F + 4 * lq];
            float4 h1 = *(const float4*)&H[(size_t)e1.x * F + 4 * lq];
            float4 h2 = *(const float4*)&H[(size_t)e2.x * F + 4 * lq];
            float4 h3 = *(const float4*)&H[(size_t)e3.x * F + 4 * lq];
            float4 h4 = *(const float4*)&H[(size_t)e4.x * F + 4 * lq];
            float4 h5 = *(const float4*)&H[(size_t)e5.x * F + 4 * lq];
            float4 h6 = *(const float4*)&H[(size_t)e6.x * F + 4 * lq];
            float4 h7 = *(const float4*)&H[(size_t)e7.x * F + 4 * lq];
            float w0 = __int_as_float(e0.y), w1 = __int_as_float(e1.y);
            float w2 = __int_as_float(e2.y), w3 = __int_as_float(e3.y);
            float w4 = __int_as_float(e4.y), w5 = __int_as_float(e5.y);
            float w6 = __int_as_float(e6.y), w7 = __int_as_float(e7.y);
            acc.x += h0.x * w0; acc.y += h0.y * w0; acc.z += h0.z * w0; acc.w += h0.w * w0;
            acc.x += h1.x * w1; acc.y += h1.y * w1; acc.z += h1.z * w1; acc.w += h1.w * w1;
            acc.x += h2.x * w2; acc.y += h2.y * w2; acc.z += h2.z * w2; acc.w += h2.w * w2;
            acc.x += h3.x * w3; acc.y += h3.y * w3; acc.z += h3.z * w3; acc.w += h3.w * w3;
            acc.x += h4.x * w4; acc.y += h4.y * w4; acc.z += h4.z * w4; acc.w += h4.w * w4;
            acc.x += h5.x * w5; acc.y += h5.y * w5; acc.z += h5.z * w5; acc.w += h5.w * w5;
            acc.x += h6.x * w6; acc.y += h6.y * w6; acc.z += h6.z * w6; acc.w += h6.w * w6;
            acc.x += h7.x * w7; acc.y += h7.y * w7; acc.z += h7.z * w7; acc.w += h7.w * w7;
        }
    }
    for (; j + 2 <= je; j += 2) {
        int2 e0 = ep[j], e1 = ep[j + 1];
        if (act) {
            float4 h0 = *(const float4*)&H[(size_t)e0.x * F + 4 * lq];
            float4 h1 = *(const float4*)&H[(size_t)e1.x * F + 4 * lq];
            float w0 = __int_as_float(e0.y), w1 = __int_as_float(e1.y);
            acc.x += h0.x * w0; acc.y += h0.y * w0; acc.z += h0.z * w0; acc.w += h0.w * w0;
            acc.x += h1.x * w1; acc.y += h1.y * w1; acc.z += h1.z * w1; acc.w += h1.w * w1;
        }
    }
    if (j < je) {
        int2 e = ep[j];
        if (act) {
            float4 h = *(const float4*)&H[(size_t)e.x * F + 4 * lq];
            float wv = __int_as_float(e.y);
            acc.x += h.x * wv; acc.y += h.y * wv; acc.z += h.z * wv; acc.w += h.w * wv;
        }
    }

    if (act) {
        float4 b = *(const float4*)&bias[4 * lq];
        acc.x += b.x; acc.y += b.y; acc.z += b.z; acc.w += b.w;
        if (RELU) {
            acc.x = fmaxf(acc.x, 0.f); acc.y = fmaxf(acc.y, 0.f);
            acc.z = fmaxf(acc.z, 0.f); acc.w = fmaxf(acc.w, 0.f);
        }
        *(float4*)&out[(size_t)node * F + 4 * lq] = acc;
    }
}

// ---------------- launch ----------------

extern "C" void kernel_launch(void* const* d_in, const int* in_sizes, int n_in,
                              void* d_out, int out_size, void* d_ws, size_t ws_size,
                              hipStream_t stream) {
    const float* x  = (const float*)d_in[0];
    const int*   ei = (const int*)d_in[1];
    const float* W0 = (const float*)d_in[2];
    const float* b0 = (const float*)d_in[3];
    const float* W1 = (const float*)d_in[4];
    const float* b1 = (const float*)d_in[5];
    const float* W2 = (const float*)d_in[6];
    const float* b2 = (const float*)d_in[7];
    float* out = (float*)d_out;

    const int N = in_sizes[0] / 128;
    const int E = in_sizes[1] / 2;
    const int NBUK = (N + 255) >> 8;   // coarse buckets of 256 nodes (<=512)

    char* w = (char*)d_ws;
    size_t off = 0;
    int*   cnt       = (int*)(w + off);   off = ALIGN256(off + (size_t)N * 4);
    int*   row_start = (int*)(w + off);   off = ALIGN256(off + (size_t)(N + 1) * 4);
    float* dinv      = (float*)(w + off); off = ALIGN256(off + (size_t)N * 4);
    int*   blk       = (int*)(w + off);   off = ALIGN256(off + 256 * 4);
    int*   cpos      = (int*)(w + off);   off = ALIGN256(off + (size_t)NBUK * 4);
    int2*  ep        = (int2*)(w + off);  off = ALIGN256(off + (size_t)E * 8);
    float* bufA      = (float*)(w + off); off = ALIGN256(off + (size_t)N * 64 * 4);
    float* bufB      = (float*)(w + off); off = ALIGN256(off + (size_t)N * 64 * 4);
    int2*  stage     = (int2*)bufB;       // dead before agg1 writes bufB

    const int gE    = (E + 255) / 256;
    const int gN    = (N + 255) / 256;
    const int NB    = (N + 1023) / 1024;
    const int gGemm = (N + 63) / 64;
    const int gAgg  = (N + 15) / 16;
    const int gPA   = (E + 8191) / 8192;

    hipMemsetAsync(cnt, 0, (size_t)N * 4, stream);
    // layer-1 GEMM with degree-count fused on trailing blocks
    k_gemm<<<gGemm + gE, 256, 0, stream>>>(x, W0, bufA, N, 128, 64, gGemm, ei, cnt, E);
    k_scan1<<<NB, 256, 0, stream>>>(cnt, row_start, blk, dinv, N);
    k_scan2<<<1, 256, 0, stream>>>(blk, NB);
    k_scan3<<<gN, 256, 0, stream>>>(row_start, blk, cpos, N, E);
    k_passA<<<gPA, 256, 0, stream>>>(ei, cpos, stage, E, NBUK);
    k_passB<<<NBUK, 256, 0, stream>>>(stage, row_start, dinv, ep, N);

    k_agg4<16, 64, 1><<<gAgg, 256, 0, stream>>>(bufA, row_start, ep, dinv, b0, bufB, N);
    k_gemm<<<gGemm, 256, 0, stream>>>(bufB, W1, bufA, N, 64, 64, gGemm, ei, cnt, 0);
    k_agg4<16, 64, 1><<<gAgg, 256, 0, stream>>>(bufA, row_start, ep, dinv, b1, bufB, N);
    k_gemm<<<gGemm, 256, 0, stream>>>(bufB, W2, bufA, N, 64, 40, gGemm, ei, cnt, 0);
    k_agg4<10, 40, 0><<<gAgg, 256, 0, stream>>>(bufA, row_start, ep, dinv, b2, out, N);
}

// Round 4
// 402.596 us; speedup vs baseline: 1.9891x; 1.2045x over previous
//
#include <hip/hip_runtime.h>

// GCN forward: 3x (GEMM -> normalized scatter-sum -> bias -> relu[except last])
// CSR-by-destination built with ZERO global atomics:
//   k_coarse: LDS-staged histogram of dst>>8 (391 coarse buckets)
//   k_cscan : 1-block exclusive scan of bucket counts -> cbase/cpos
//   k_passA : coarse scatter of (src,dst) into bucket runs (LDS-staged appends)
//   k_B1    : per bucket: LDS-atomic per-node count + LDS scan -> row_start, dinv
//   k_B2    : per bucket: fine scatter -> ep = (src, norm), all writes L2-local
// Aggregation: 16 lanes/node (float4 per lane), 4 nodes/wave, unroll x8.

#define ALIGN256(x) (((size_t)(x) + 255) & ~(size_t)255)

// ---------------- coarse histogram ----------------

__global__ __launch_bounds__(256) void k_coarse(const int* __restrict__ ei,
                                                int* __restrict__ ccnt,
                                                int E, int NBUK) {
    __shared__ int h[512];
    int t = threadIdx.x;
    for (int i = t; i < NBUK; i += 256) h[i] = 0;
    __syncthreads();
    int e0 = blockIdx.x * 8192;
    int e1 = min(e0 + 8192, E);
    for (int e = e0 + t; e < e1; e += 256) atomicAdd(&h[ei[E + e] >> 8], 1);
    __syncthreads();
    for (int i = t; i < NBUK; i += 256) {
        int c = h[i];
        if (c) atomicAdd(&ccnt[i], c);
    }
}

// ---------------- scan of coarse counts (single block, <=512 buckets) -------

__global__ __launch_bounds__(256) void k_cscan(const int* __restrict__ ccnt,
                                               int* __restrict__ cbase,
                                               int* __restrict__ cpos,
                                               int* __restrict__ row_start,
                                               int NBUK, int E, int N) {
    __shared__ int sd[256];
    int t = threadIdx.x;
    int i0 = 2 * t, i1 = 2 * t + 1;
    int v0 = (i0 < NBUK) ? ccnt[i0] : 0;
    int v1 = (i1 < NBUK) ? ccnt[i1] : 0;
    int s = v0 + v1;
    sd[t] = s;
    __syncthreads();
    for (int off = 1; off < 256; off <<= 1) {
        int u = (t >= off) ? sd[t - off] : 0;
        __syncthreads();
        sd[t] += u;
        __syncthreads();
    }
    int base = sd[t] - s;
    if (i0 < NBUK) { cbase[i0] = base;      cpos[i0] = base; }
    if (i1 < NBUK) { cbase[i1] = base + v0; cpos[i1] = base + v0; }
    if (t == 0) { cbase[NBUK] = E; row_start[N] = E; }
}

// ---------------- pass A: coarse scatter (LDS-staged contiguous runs) -------

__global__ __launch_bounds__(256) void k_passA(const int* __restrict__ ei,
                                               int* __restrict__ cpos,
                                               int2* __restrict__ stage,
                                               int E, int NBUK) {
    __shared__ int h[512];
    __shared__ int base[512];
    int t = threadIdx.x;
    for (int i = t; i < NBUK; i += 256) h[i] = 0;
    __syncthreads();
    int e0 = blockIdx.x * 8192;
    int e1 = min(e0 + 8192, E);
    for (int e = e0 + t; e < e1; e += 256) atomicAdd(&h[ei[E + e] >> 8], 1);
    __syncthreads();
    for (int b = t; b < NBUK; b += 256) {
        int c = h[b];
        base[b] = c ? atomicAdd(&cpos[b], c) : 0;
        h[b] = 0;
    }
    __syncthreads();
    for (int e = e0 + t; e < e1; e += 256) {
        int s = ei[e];
        int d = ei[E + e];
        int b = d >> 8;
        int off = base[b] + atomicAdd(&h[b], 1);
        stage[off] = make_int2(s, d);
    }
}

// ---------------- B1: per-bucket node counts (LDS atomics) -> row_start, dinv

__global__ __launch_bounds__(256) void k_B1(const int2* __restrict__ stage,
                                            const int* __restrict__ cbase,
                                            int* __restrict__ row_start,
                                            float* __restrict__ dinv, int N) {
    __shared__ int cnt[256];
    __shared__ int sd[256];
    int b = blockIdx.x;
    int n0 = b << 8;
    int t = threadIdx.x;
    cnt[t] = 0;
    __syncthreads();
    int s0 = cbase[b], s1 = cbase[b + 1];
    for (int j = s0 + t; j < s1; j += 256) atomicAdd(&cnt[stage[j].y & 255], 1);
    __syncthreads();
    int c = cnt[t];
    sd[t] = c;
    __syncthreads();
    for (int off = 1; off < 256; off <<= 1) {
        int u = (t >= off) ? sd[t - off] : 0;
        __syncthreads();
        sd[t] += u;
        __syncthreads();
    }
    int excl = sd[t] - c;
    int node = n0 + t;
    if (node < N) {
        row_start[node] = s0 + excl;
        dinv[node] = 1.0f / sqrtf((float)(c + 1));   // +1 self-loop
    }
}

// ---------------- B2: fine scatter within bucket -> ep = (src, norm) --------

__global__ __launch_bounds__(256) void k_B2(const int2* __restrict__ stage,
                                            const int* __restrict__ cbase,
                                            const int* __restrict__ row_start,
                                            const float* __restrict__ dinv,
                                            int2* __restrict__ ep, int N) {
    __shared__ int lpos[256];
    __shared__ float ld[256];
    int b = blockIdx.x;
    int n0 = b << 8;
    int t = threadIdx.x;
    int node = n0 + t;
    if (node < N) {
        lpos[t] = row_start[node];
        ld[t] = dinv[node];
    }
    __syncthreads();
    int s0 = cbase[b], s1 = cbase[b + 1];
    for (int j = s0 + t; j < s1; j += 256) {
        int2 sd2 = stage[j];
        int li = sd2.y & 255;
        int slot = atomicAdd(&lpos[li], 1);
        ep[slot] = make_int2(sd2.x, __float_as_int(dinv[sd2.x] * ld[li]));
    }
}

// ---------------- GEMM: Y[N,OUT] = X[N,K] @ W[K,OUT] ----------------
// 64 rows x 64 cols per 256-thread block, 4x4 register tile, K tiled by 32.
// Wl staged per 32-k slab (8 KB) -> LDS 17.2 KB total -> 4 blocks/CU (reg-capped).
// Thread rows {ty, ty+16, ty+32, ty+48}: A-tile LDS reads spread all 32 banks.

template <int K, int OUT>
__global__ __launch_bounds__(256) void k_gemm(const float* __restrict__ X,
                                              const float* __restrict__ W,
                                              float* __restrict__ Y, int N) {
    __shared__ float Wl[32 * 64];    // 8 KB, current k-slab, zero-padded to 64 cols
    __shared__ float Al[64 * 36];    // 9 KB, padded stride 36
    int tid = threadIdx.x;
    int tx = tid & 15;
    int ty = tid >> 4;
    int row0 = blockIdx.x * 64;

    float acc[4][4];
#pragma unroll
    for (int i = 0; i < 4; i++)
#pragma unroll
        for (int j = 0; j < 4; j++) acc[i][j] = 0.0f;

    for (int kt = 0; kt < K; kt += 32) {
        __syncthreads();
        // W slab: 32 rows x 64 cols as float4 (512 slots, 2 per thread)
#pragma unroll
        for (int it = 0; it < 2; it++) {
            int idx = tid + it * 256;
            int k = idx >> 4;
            int c4 = (idx & 15) << 2;
            float4 v = make_float4(0.f, 0.f, 0.f, 0.f);
            if (c4 < OUT) v = *(const float4*)&W[(size_t)(kt + k) * OUT + c4];
            *(float4*)&Wl[k * 64 + c4] = v;
        }
        // A tile: 64 rows x 32 k as float4 (512 slots)
#pragma unroll
        for (int it = 0; it < 2; it++) {
            int vid = tid + it * 256;
            int r = vid >> 3;
            int kk = (vid & 7) << 2;
            int row = row0 + r;
            float4 v = make_float4(0.f, 0.f, 0.f, 0.f);
            if (row < N) v = *(const float4*)&X[(size_t)row * K + kt + kk];
            *(float4*)&Al[r * 36 + kk] = v;
        }
        __syncthreads();
#pragma unroll
        for (int k = 0; k < 32; k += 4) {
            float4 a[4], w[4];
#pragma unroll
            for (int i = 0; i < 4; i++) a[i] = *(const float4*)&Al[(ty + 16 * i) * 36 + k];
#pragma unroll
            for (int j = 0; j < 4; j++) w[j] = *(const float4*)&Wl[(k + j) * 64 + 4 * tx];
#pragma unroll
            for (int i = 0; i < 4; i++) {
                acc[i][0] += a[i].x * w[0].x; acc[i][1] += a[i].x * w[0].y;
                acc[i][2] += a[i].x * w[0].z; acc[i][3] += a[i].x * w[0].w;
                acc[i][0] += a[i].y * w[1].x; acc[i][1] += a[i].y * w[1].y;
                acc[i][2] += a[i].y * w[1].z; acc[i][3] += a[i].y * w[1].w;
                acc[i][0] += a[i].z * w[2].x; acc[i][1] += a[i].z * w[2].y;
                acc[i][2] += a[i].z * w[2].z; acc[i][3] += a[i].z * w[2].w;
                acc[i][0] += a[i].w * w[3].x; acc[i][1] += a[i].w * w[3].y;
                acc[i][2] += a[i].w * w[3].z; acc[i][3] += a[i].w * w[3].w;
            }
        }
    }

    int c0 = 4 * tx;
#pragma unroll
    for (int i = 0; i < 4; i++) {
        int row = row0 + ty + 16 * i;
        if (row < N && c0 + 4 <= OUT) {
            *(float4*)&Y[(size_t)row * OUT + c0] =
                make_float4(acc[i][0], acc[i][1], acc[i][2], acc[i][3]);
        }
    }
}

// ---------------- Aggregation ----------------
// 16 lanes per node (lane = float4 of features), 4 nodes/wave, unroll x8.

template <int NV, int F, int RELU>
__global__ __launch_bounds__(256) void k_agg4(const float* __restrict__ H,
                                              const int* __restrict__ row_start,
                                              const int2* __restrict__ ep,
                                              const float* __restrict__ dinv,
                                              const float* __restrict__ bias,
                                              float* __restrict__ out, int N) {
    int tid = threadIdx.x;
    int lane = tid & 63;
    int sub = lane >> 4;
    int lq = lane & 15;
    int node = blockIdx.x * 16 + (tid >> 6) * 4 + sub;
    if (node >= N) return;
    const bool act = (lq < NV);

    int jb = row_start[node];
    int je = row_start[node + 1];
    float dv = dinv[node];

    float4 acc = make_float4(0.f, 0.f, 0.f, 0.f);
    if (act) {
        float4 h = *(const float4*)&H[(size_t)node * F + 4 * lq];
        float s2 = dv * dv;
        acc.x = h.x * s2; acc.y = h.y * s2; acc.z = h.z * s2; acc.w = h.w * s2;
    }

    int j = jb;
    for (; j + 8 <= je; j += 8) {
        int2 e0 = ep[j],     e1 = ep[j + 1], e2 = ep[j + 2], e3 = ep[j + 3];
        int2 e4 = ep[j + 4], e5 = ep[j + 5], e6 = ep[j + 6], e7 = ep[j + 7];
        if (act) {
            float4 h0 = *(const float4*)&H[(size_t)e0.x * F + 4 * lq];
            float4 h1 = *(const float4*)&H[(size_t)e1.x * F + 4 * lq];
            float4 h2 = *(const float4*)&H[(size_t)e2.x * F + 4 * lq];
            float4 h3 = *(const float4*)&H[(size_t)e3.x * F + 4 * lq];
            float4 h4 = *(const float4*)&H[(size_t)e4.x * F + 4 * lq];
            float4 h5 = *(const float4*)&H[(size_t)e5.x * F + 4 * lq];
            float4 h6 = *(const float4*)&H[(size_t)e6.x * F + 4 * lq];
            float4 h7 = *(const float4*)&H[(size_t)e7.x * F + 4 * lq];
            float w0 = __int_as_float(e0.y), w1 = __int_as_float(e1.y);
            float w2 = __int_as_float(e2.y), w3 = __int_as_float(e3.y);
            float w4 = __int_as_float(e4.y), w5 = __int_as_float(e5.y);
            float w6 = __int_as_float(e6.y), w7 = __int_as_float(e7.y);
            acc.x += h0.x * w0; acc.y += h0.y * w0; acc.z += h0.z * w0; acc.w += h0.w * w0;
            acc.x += h1.x * w1; acc.y += h1.y * w1; acc.z += h1.z * w1; acc.w += h1.w * w1;
            acc.x += h2.x * w2; acc.y += h2.y * w2; acc.z += h2.z * w2; acc.w += h2.w * w2;
            acc.x += h3.x * w3; acc.y += h3.y * w3; acc.z += h3.z * w3; acc.w += h3.w * w3;
            acc.x += h4.x * w4; acc.y += h4.y * w4; acc.z += h4.z * w4; acc.w += h4.w * w4;
            acc.x += h5.x * w5; acc.y += h5.y * w5; acc.z += h5.z * w5; acc.w += h5.w * w5;
            acc.x += h6.x * w6; acc.y += h6.y * w6; acc.z += h6.z * w6; acc.w += h6.w * w6;
            acc.x += h7.x * w7; acc.y += h7.y * w7; acc.z += h7.z * w7; acc.w += h7.w * w7;
        }
    }
    for (; j + 2 <= je; j += 2) {
        int2 e0 = ep[j], e1 = ep[j + 1];
        if (act) {
            float4 h0 = *(const float4*)&H[(size_t)e0.x * F + 4 * lq];
            float4 h1 = *(const float4*)&H[(size_t)e1.x * F + 4 * lq];
            float w0 = __int_as_float(e0.y), w1 = __int_as_float(e1.y);
            acc.x += h0.x * w0; acc.y += h0.y * w0; acc.z += h0.z * w0; acc.w += h0.w * w0;
            acc.x += h1.x * w1; acc.y += h1.y * w1; acc.z += h1.z * w1; acc.w += h1.w * w1;
        }
    }
    if (j < je) {
        int2 e = ep[j];
        if (act) {
            float4 h = *(const float4*)&H[(size_t)e.x * F + 4 * lq];
            float wv = __int_as_float(e.y);
            acc.x += h.x * wv; acc.y += h.y * wv; acc.z += h.z * wv; acc.w += h.w * wv;
        }
    }

    if (act) {
        float4 b = *(const float4*)&bias[4 * lq];
        acc.x += b.x; acc.y += b.y; acc.z += b.z; acc.w += b.w;
        if (RELU) {
            acc.x = fmaxf(acc.x, 0.f); acc.y = fmaxf(acc.y, 0.f);
            acc.z = fmaxf(acc.z, 0.f); acc.w = fmaxf(acc.w, 0.f);
        }
        *(float4*)&out[(size_t)node * F + 4 * lq] = acc;
    }
}

// ---------------- launch ----------------

extern "C" void kernel_launch(void* const* d_in, const int* in_sizes, int n_in,
                              void* d_out, int out_size, void* d_ws, size_t ws_size,
                              hipStream_t stream) {
    const float* x  = (const float*)d_in[0];
    const int*   ei = (const int*)d_in[1];
    const float* W0 = (const float*)d_in[2];
    const float* b0 = (const float*)d_in[3];
    const float* W1 = (const float*)d_in[4];
    const float* b1 = (const float*)d_in[5];
    const float* W2 = (const float*)d_in[6];
    const float* b2 = (const float*)d_in[7];
    float* out = (float*)d_out;

    const int N = in_sizes[0] / 128;
    const int E = in_sizes[1] / 2;
    const int NBUK = (N + 255) >> 8;   // coarse buckets of 256 nodes (<=512)

    char* w = (char*)d_ws;
    size_t off = 0;
    int*   ccnt      = (int*)(w + off);   off = ALIGN256(off + (size_t)NBUK * 4);
    int*   cbase     = (int*)(w + off);   off = ALIGN256(off + (size_t)(NBUK + 1) * 4);
    int*   cpos      = (int*)(w + off);   off = ALIGN256(off + (size_t)NBUK * 4);
    int*   row_start = (int*)(w + off);   off = ALIGN256(off + (size_t)(N + 1) * 4);
    float* dinv      = (float*)(w + off); off = ALIGN256(off + (size_t)N * 4);
    int2*  ep        = (int2*)(w + off);  off = ALIGN256(off + (size_t)E * 8);
    float* bufA      = (float*)(w + off); off = ALIGN256(off + (size_t)N * 64 * 4);
    float* bufB      = (float*)(w + off); off = ALIGN256(off + (size_t)N * 64 * 4);
    int2*  stage     = (int2*)bufB;       // dead before agg1 writes bufB

    const int gGemm = (N + 63) / 64;
    const int gAgg  = (N + 15) / 16;
    const int gPA   = (E + 8191) / 8192;

    hipMemsetAsync(ccnt, 0, (size_t)NBUK * 4, stream);
    k_gemm<128, 64><<<gGemm, 256, 0, stream>>>(x, W0, bufA, N);
    k_coarse<<<gPA, 256, 0, stream>>>(ei, ccnt, E, NBUK);
    k_cscan<<<1, 256, 0, stream>>>(ccnt, cbase, cpos, row_start, NBUK, E, N);
    k_passA<<<gPA, 256, 0, stream>>>(ei, cpos, stage, E, NBUK);
    k_B1<<<NBUK, 256, 0, stream>>>(stage, cbase, row_start, dinv, N);
    k_B2<<<NBUK, 256, 0, stream>>>(stage, cbase, row_start, dinv, ep, N);

    k_agg4<16, 64, 1><<<gAgg, 256, 0, stream>>>(bufA, row_start, ep, dinv, b0, bufB, N);
    k_gemm<64, 64><<<gGemm, 256, 0, stream>>>(bufB, W1, bufA, N);
    k_agg4<16, 64, 1><<<gAgg, 256, 0, stream>>>(bufA, row_start, ep, dinv, b1, bufB, N);
    k_gemm<64, 40><<<gGemm, 256, 0, stream>>>(bufB, W2, bufA, N);
    k_agg4<10, 40, 0><<<gAgg, 256, 0, stream>>>(bufA, row_start, ep, dinv, b2, out, N);
}

// Round 5
// 326.620 us; speedup vs baseline: 2.4518x; 1.2326x over previous
//
#include <hip/hip_runtime.h>
#include <hip/hip_fp16.h>

// GCN forward: 3x (GEMM -> normalized scatter-sum -> bias -> relu[except last])
// Gathered intermediates are fp16 (halves the random-gather table: 25.6->12.8MB,
// doubles effective L2 coverage). Agg: 8 lanes/node (8 fp16 feats = 16B per
// lane), 8 nodes/wave, unroll x8. CSR built with zero global atomics via
// coarse(256-node)+fine LDS-staged partition; stage entries packed to 4B.

#define ALIGN256(x) (((size_t)(x) + 255) & ~(size_t)255)

// ---------------- coarse histogram ----------------

__global__ __launch_bounds__(256) void k_coarse(const int* __restrict__ ei,
                                                int* __restrict__ ccnt,
                                                int E, int NBUK) {
    __shared__ int h[512];
    int t = threadIdx.x;
    for (int i = t; i < NBUK; i += 256) h[i] = 0;
    __syncthreads();
    int e0 = blockIdx.x * 8192;
    int e1 = min(e0 + 8192, E);
    for (int e = e0 + t; e < e1; e += 256) atomicAdd(&h[ei[E + e] >> 8], 1);
    __syncthreads();
    for (int i = t; i < NBUK; i += 256) {
        int c = h[i];
        if (c) atomicAdd(&ccnt[i], c);
    }
}

// ---------------- scan of coarse counts (single block, <=512 buckets) -------

__global__ __launch_bounds__(256) void k_cscan(const int* __restrict__ ccnt,
                                               int* __restrict__ cbase,
                                               int* __restrict__ cpos,
                                               int* __restrict__ row_start,
                                               int NBUK, int E, int N) {
    __shared__ int sd[256];
    int t = threadIdx.x;
    int i0 = 2 * t, i1 = 2 * t + 1;
    int v0 = (i0 < NBUK) ? ccnt[i0] : 0;
    int v1 = (i1 < NBUK) ? ccnt[i1] : 0;
    int s = v0 + v1;
    sd[t] = s;
    __syncthreads();
    for (int off = 1; off < 256; off <<= 1) {
        int u = (t >= off) ? sd[t - off] : 0;
        __syncthreads();
        sd[t] += u;
        __syncthreads();
    }
    int base = sd[t] - s;
    if (i0 < NBUK) { cbase[i0] = base;      cpos[i0] = base; }
    if (i1 < NBUK) { cbase[i1] = base + v0; cpos[i1] = base + v0; }
    if (t == 0) { cbase[NBUK] = E; row_start[N] = E; }
}

// ---------------- pass A: coarse scatter; stage entry = (dst&255)<<24 | src -

__global__ __launch_bounds__(256) void k_passA(const int* __restrict__ ei,
                                               int* __restrict__ cpos,
                                               unsigned int* __restrict__ stage,
                                               int E, int NBUK) {
    __shared__ int h[512];
    __shared__ int base[512];
    int t = threadIdx.x;
    for (int i = t; i < NBUK; i += 256) h[i] = 0;
    __syncthreads();
    int e0 = blockIdx.x * 8192;
    int e1 = min(e0 + 8192, E);
    for (int e = e0 + t; e < e1; e += 256) atomicAdd(&h[ei[E + e] >> 8], 1);
    __syncthreads();
    for (int b = t; b < NBUK; b += 256) {
        int c = h[b];
        base[b] = c ? atomicAdd(&cpos[b], c) : 0;
        h[b] = 0;
    }
    __syncthreads();
    for (int e = e0 + t; e < e1; e += 256) {
        unsigned int s = (unsigned int)ei[e];
        int d = ei[E + e];
        int b = d >> 8;
        int off = base[b] + atomicAdd(&h[b], 1);
        stage[off] = ((unsigned int)(d & 255) << 24) | s;
    }
}

// ---------------- B1: per-bucket node counts (LDS atomics) -> row_start, dinv

__global__ __launch_bounds__(256) void k_B1(const unsigned int* __restrict__ stage,
                                            const int* __restrict__ cbase,
                                            int* __restrict__ row_start,
                                            float* __restrict__ dinv, int N) {
    __shared__ int cnt[256];
    __shared__ int sd[256];
    int b = blockIdx.x;
    int n0 = b << 8;
    int t = threadIdx.x;
    cnt[t] = 0;
    __syncthreads();
    int s0 = cbase[b], s1 = cbase[b + 1];
    for (int j = s0 + t; j < s1; j += 256) atomicAdd(&cnt[stage[j] >> 24], 1);
    __syncthreads();
    int c = cnt[t];
    sd[t] = c;
    __syncthreads();
    for (int off = 1; off < 256; off <<= 1) {
        int u = (t >= off) ? sd[t - off] : 0;
        __syncthreads();
        sd[t] += u;
        __syncthreads();
    }
    int excl = sd[t] - c;
    int node = n0 + t;
    if (node < N) {
        row_start[node] = s0 + excl;
        dinv[node] = 1.0f / sqrtf((float)(c + 1));   // +1 self-loop
    }
}

// ---------------- B2: fine scatter within bucket -> ep = (src, norm) --------

__global__ __launch_bounds__(256) void k_B2(const unsigned int* __restrict__ stage,
                                            const int* __restrict__ cbase,
                                            const int* __restrict__ row_start,
                                            const float* __restrict__ dinv,
                                            int2* __restrict__ ep, int N) {
    __shared__ int lpos[256];
    __shared__ float ld[256];
    int b = blockIdx.x;
    int n0 = b << 8;
    int t = threadIdx.x;
    int node = n0 + t;
    if (node < N) {
        lpos[t] = row_start[node];
        ld[t] = dinv[node];
    }
    __syncthreads();
    int s0 = cbase[b], s1 = cbase[b + 1];
    for (int j = s0 + t; j < s1; j += 256) {
        unsigned int v = stage[j];
        int li = v >> 24;
        int src = v & 0xFFFFFF;
        int slot = atomicAdd(&lpos[li], 1);
        ep[slot] = make_int2(src, __float_as_int(dinv[src] * ld[li]));
    }
}

// ---------------- GEMM: Y[N,OUT](fp16) = X[N,K](fp32) @ W[K,OUT] ------------
// 64 rows x 64 cols per 256-thread block, 4x4 register tile, K tiled by 32.
// Wl staged per 32-k slab (8 KB); thread rows {ty,ty+16,ty+32,ty+48} spread
// A-tile LDS reads across all 32 banks.

template <int K, int OUT>
__global__ __launch_bounds__(256) void k_gemm(const float* __restrict__ X,
                                              const float* __restrict__ W,
                                              __half* __restrict__ Y, int N) {
    __shared__ float Wl[32 * 64];    // 8 KB, current k-slab, zero-padded cols
    __shared__ float Al[64 * 36];    // 9 KB, padded stride 36
    int tid = threadIdx.x;
    int tx = tid & 15;
    int ty = tid >> 4;
    int row0 = blockIdx.x * 64;

    float acc[4][4];
#pragma unroll
    for (int i = 0; i < 4; i++)
#pragma unroll
        for (int j = 0; j < 4; j++) acc[i][j] = 0.0f;

    for (int kt = 0; kt < K; kt += 32) {
        __syncthreads();
#pragma unroll
        for (int it = 0; it < 2; it++) {
            int idx = tid + it * 256;
            int k = idx >> 4;
            int c4 = (idx & 15) << 2;
            float4 v = make_float4(0.f, 0.f, 0.f, 0.f);
            if (c4 < OUT) v = *(const float4*)&W[(size_t)(kt + k) * OUT + c4];
            *(float4*)&Wl[k * 64 + c4] = v;
        }
#pragma unroll
        for (int it = 0; it < 2; it++) {
            int vid = tid + it * 256;
            int r = vid >> 3;
            int kk = (vid & 7) << 2;
            int row = row0 + r;
            float4 v = make_float4(0.f, 0.f, 0.f, 0.f);
            if (row < N) v = *(const float4*)&X[(size_t)row * K + kt + kk];
            *(float4*)&Al[r * 36 + kk] = v;
        }
        __syncthreads();
#pragma unroll
        for (int k = 0; k < 32; k += 4) {
            float4 a[4], w[4];
#pragma unroll
            for (int i = 0; i < 4; i++) a[i] = *(const float4*)&Al[(ty + 16 * i) * 36 + k];
#pragma unroll
            for (int j = 0; j < 4; j++) w[j] = *(const float4*)&Wl[(k + j) * 64 + 4 * tx];
#pragma unroll
            for (int i = 0; i < 4; i++) {
                acc[i][0] += a[i].x * w[0].x; acc[i][1] += a[i].x * w[0].y;
                acc[i][2] += a[i].x * w[0].z; acc[i][3] += a[i].x * w[0].w;
                acc[i][0] += a[i].y * w[1].x; acc[i][1] += a[i].y * w[1].y;
                acc[i][2] += a[i].y * w[1].z; acc[i][3] += a[i].y * w[1].w;
                acc[i][0] += a[i].z * w[2].x; acc[i][1] += a[i].z * w[2].y;
                acc[i][2] += a[i].z * w[2].z; acc[i][3] += a[i].z * w[2].w;
                acc[i][0] += a[i].w * w[3].x; acc[i][1] += a[i].w * w[3].y;
                acc[i][2] += a[i].w * w[3].z; acc[i][3] += a[i].w * w[3].w;
            }
        }
    }

    int c0 = 4 * tx;
#pragma unroll
    for (int i = 0; i < 4; i++) {
        int row = row0 + ty + 16 * i;
        if (row < N && c0 + 4 <= OUT) {
            __half2 p0 = __floats2half2_rn(acc[i][0], acc[i][1]);
            __half2 p1 = __floats2half2_rn(acc[i][2], acc[i][3]);
            uint2 pk = make_uint2(*(unsigned int*)&p0, *(unsigned int*)&p1);
            *(uint2*)&Y[(size_t)row * OUT + c0] = pk;   // 8B store, 8B-aligned
        }
    }
}

// ---------------- Aggregation (fp16 gather, fp32 accumulate) ----------------
// 8 lanes per node (lane = 8 fp16 features = 16B), 8 nodes/wave, unroll x8:
// up to 64 independent 16B gathers in flight per wave.

__device__ __forceinline__ void fma8(float4& a0, float4& a1, uint4 hv, float w) {
    __half2* hp = (__half2*)&hv;
    float2 f0 = __half22float2(hp[0]);
    float2 f1 = __half22float2(hp[1]);
    float2 f2 = __half22float2(hp[2]);
    float2 f3 = __half22float2(hp[3]);
    a0.x += f0.x * w; a0.y += f0.y * w; a0.z += f1.x * w; a0.w += f1.y * w;
    a1.x += f2.x * w; a1.y += f2.y * w; a1.z += f3.x * w; a1.w += f3.y * w;
}

template <int NV, int F, int RELU>
__global__ __launch_bounds__(256) void k_agg8(const __half* __restrict__ H,
                                              const int* __restrict__ row_start,
                                              const int2* __restrict__ ep,
                                              const float* __restrict__ dinv,
                                              const float* __restrict__ bias,
                                              float* __restrict__ out, int N) {
    int tid = threadIdx.x;
    int lane = tid & 63;
    int sub = lane >> 3;        // node within wave (0..7)
    int lq = lane & 7;          // 8-feature chunk within node row
    int node = blockIdx.x * 32 + (tid >> 6) * 8 + sub;
    if (node >= N) return;
    const bool act = (lq < NV);

    int jb = row_start[node];
    int je = row_start[node + 1];
    float dv = dinv[node];

    float4 a0 = make_float4(0.f, 0.f, 0.f, 0.f);
    float4 a1 = make_float4(0.f, 0.f, 0.f, 0.f);
    if (act) {
        uint4 hv = *(const uint4*)&H[(size_t)node * F + 8 * lq];
        fma8(a0, a1, hv, dv * dv);
    }

    int j = jb;
    for (; j + 8 <= je; j += 8) {
        int2 e0 = ep[j],     e1 = ep[j + 1], e2 = ep[j + 2], e3 = ep[j + 3];
        int2 e4 = ep[j + 4], e5 = ep[j + 5], e6 = ep[j + 6], e7 = ep[j + 7];
        if (act) {
            uint4 h0 = *(const uint4*)&H[(size_t)e0.x * F + 8 * lq];
            uint4 h1 = *(const uint4*)&H[(size_t)e1.x * F + 8 * lq];
            uint4 h2 = *(const uint4*)&H[(size_t)e2.x * F + 8 * lq];
            uint4 h3 = *(const uint4*)&H[(size_t)e3.x * F + 8 * lq];
            uint4 h4 = *(const uint4*)&H[(size_t)e4.x * F + 8 * lq];
            uint4 h5 = *(const uint4*)&H[(size_t)e5.x * F + 8 * lq];
            uint4 h6 = *(const uint4*)&H[(size_t)e6.x * F + 8 * lq];
            uint4 h7 = *(const uint4*)&H[(size_t)e7.x * F + 8 * lq];
            fma8(a0, a1, h0, __int_as_float(e0.y));
            fma8(a0, a1, h1, __int_as_float(e1.y));
            fma8(a0, a1, h2, __int_as_float(e2.y));
            fma8(a0, a1, h3, __int_as_float(e3.y));
            fma8(a0, a1, h4, __int_as_float(e4.y));
            fma8(a0, a1, h5, __int_as_float(e5.y));
            fma8(a0, a1, h6, __int_as_float(e6.y));
            fma8(a0, a1, h7, __int_as_float(e7.y));
        }
    }
    for (; j + 2 <= je; j += 2) {
        int2 e0 = ep[j], e1 = ep[j + 1];
        if (act) {
            uint4 h0 = *(const uint4*)&H[(size_t)e0.x * F + 8 * lq];
            uint4 h1 = *(const uint4*)&H[(size_t)e1.x * F + 8 * lq];
            fma8(a0, a1, h0, __int_as_float(e0.y));
            fma8(a0, a1, h1, __int_as_float(e1.y));
        }
    }
    if (j < je) {
        int2 e = ep[j];
        if (act) {
            uint4 h = *(const uint4*)&H[(size_t)e.x * F + 8 * lq];
            fma8(a0, a1, h, __int_as_float(e.y));
        }
    }

    if (act) {
        float4 b0 = *(const float4*)&bias[8 * lq];
        float4 b1 = *(const float4*)&bias[8 * lq + 4];
        a0.x += b0.x; a0.y += b0.y; a0.z += b0.z; a0.w += b0.w;
        a1.x += b1.x; a1.y += b1.y; a1.z += b1.z; a1.w += b1.w;
        if (RELU) {
            a0.x = fmaxf(a0.x, 0.f); a0.y = fmaxf(a0.y, 0.f);
            a0.z = fmaxf(a0.z, 0.f); a0.w = fmaxf(a0.w, 0.f);
            a1.x = fmaxf(a1.x, 0.f); a1.y = fmaxf(a1.y, 0.f);
            a1.z = fmaxf(a1.z, 0.f); a1.w = fmaxf(a1.w, 0.f);
        }
        *(float4*)&out[(size_t)node * F + 8 * lq] = a0;
        *(float4*)&out[(size_t)node * F + 8 * lq + 4] = a1;
    }
}

// ---------------- launch ----------------

extern "C" void kernel_launch(void* const* d_in, const int* in_sizes, int n_in,
                              void* d_out, int out_size, void* d_ws, size_t ws_size,
                              hipStream_t stream) {
    const float* x  = (const float*)d_in[0];
    const int*   ei = (const int*)d_in[1];
    const float* W0 = (const float*)d_in[2];
    const float* b0 = (const float*)d_in[3];
    const float* W1 = (const float*)d_in[4];
    const float* b1 = (const float*)d_in[5];
    const float* W2 = (const float*)d_in[6];
    const float* b2 = (const float*)d_in[7];
    float* out = (float*)d_out;

    const int N = in_sizes[0] / 128;
    const int E = in_sizes[1] / 2;
    const int NBUK = (N + 255) >> 8;   // coarse buckets of 256 nodes (<=512)

    char* w = (char*)d_ws;
    size_t off = 0;
    int*   ccnt      = (int*)(w + off);   off = ALIGN256(off + (size_t)NBUK * 4);
    int*   cbase     = (int*)(w + off);   off = ALIGN256(off + (size_t)(NBUK + 1) * 4);
    int*   cpos      = (int*)(w + off);   off = ALIGN256(off + (size_t)NBUK * 4);
    int*   row_start = (int*)(w + off);   off = ALIGN256(off + (size_t)(N + 1) * 4);
    float* dinv      = (float*)(w + off); off = ALIGN256(off + (size_t)N * 4);
    int2*  ep        = (int2*)(w + off);  off = ALIGN256(off + (size_t)E * 8);
    __half* bufH     = (__half*)(w + off); off = ALIGN256(off + (size_t)N * 64 * 2);
    float* bufF      = (float*)(w + off); off = ALIGN256(off + (size_t)N * 64 * 4);
    unsigned int* stage = (unsigned int*)bufF;   // dead before agg1 writes bufF

    const int gGemm = (N + 63) / 64;
    const int gAgg  = (N + 31) / 32;
    const int gPA   = (E + 8191) / 8192;

    hipMemsetAsync(ccnt, 0, (size_t)NBUK * 4, stream);
    k_gemm<128, 64><<<gGemm, 256, 0, stream>>>(x, W0, bufH, N);
    k_coarse<<<gPA, 256, 0, stream>>>(ei, ccnt, E, NBUK);
    k_cscan<<<1, 256, 0, stream>>>(ccnt, cbase, cpos, row_start, NBUK, E, N);
    k_passA<<<gPA, 256, 0, stream>>>(ei, cpos, stage, E, NBUK);
    k_B1<<<NBUK, 256, 0, stream>>>(stage, cbase, row_start, dinv, N);
    k_B2<<<NBUK, 256, 0, stream>>>(stage, cbase, row_start, dinv, ep, N);

    k_agg8<8, 64, 1><<<gAgg, 256, 0, stream>>>(bufH, row_start, ep, dinv, b0, bufF, N);
    k_gemm<64, 64><<<gGemm, 256, 0, stream>>>(bufF, W1, bufH, N);
    k_agg8<8, 64, 1><<<gAgg, 256, 0, stream>>>(bufH, row_start, ep, dinv, b1, bufF, N);
    k_gemm<64, 40><<<gGemm, 256, 0, stream>>>(bufF, W2, bufH, N);
    k_agg8<5, 40, 0><<<gAgg, 256, 0, stream>>>(bufH, row_start, ep, dinv, b2, out, N);
}